// Round 13
// baseline (53.619 us; speedup 1.0000x reference)
//
#include <hip/hip_runtime.h>
#include <hip/hip_fp16.h>

// SSIM loss — round 13: f16 input staging, branch-free P2.
// P1: stage (a,b) as __half2, zero-padded halo, 42x84 (stride 84 -> even
//     bank spread), 14.1KB. All global loads live here (2 iters, high TLP).
// P2: branch-free: 6 ds_read_b128 + QC build + 176 hfma2; paired b128 sPm
//     stores. P3: v-conv 4 rows/thread, imm-offset b64 reads (r12).
// 512 threads, LDS 35.6KB -> 4 blocks/CU = 32 waves (100% static ceiling).

#define IMGH 512
#define IMGW 512
#define TW 64
#define TH 32
#define HRR 42            // TH + 10 h-rows
#define SAB_STRIDE 84     // half2 stride; 336B -> even 4-bank-group spread
#define C1F 1.0e-4f
#define C2F 9.0e-4f
#define GX 8
#define GY 16
#define GZ 48
#define NBLOCKS (GX * GY * GZ)   // 6144
#define NPIX (16 * 3 * 512 * 512)

// Gaussian weights, sigma=1.5, ws=11 (validated r1-r12).
#define W0 0.0010283818f
#define W1 0.0075987503f
#define W2 0.0360007547f
#define W3 0.1093606960f
#define W4 0.2130055367f
#define W5 0.2660117184f

struct alignas(8) H4 { __half2 ab; __half2 qc; };  // (sa,sb) , (saa+sbb, sab)

static __device__ __forceinline__ __half2 pkrtz(float a, float b) {
    auto r = __builtin_amdgcn_cvt_pkrtz(a, b);   // __fp16 ext_vector(2)
    return *reinterpret_cast<__half2*>(&r);
}

__global__ __launch_bounds__(512, 4)
void ssim_tile(const float* __restrict__ img1, const float* __restrict__ img2,
               float* __restrict__ partials) {
    __shared__ __half2 sAB[HRR][SAB_STRIDE];   // 14,112 B ; col l -> sAB[row][l]
    __shared__ H4 sPm[HRR][64];                // 21,504 B, stride 512B
    __shared__ float wsum[8];

    const float W[11] = {W0, W1, W2, W3, W4, W5, W4, W3, W2, W1, W0};
    __half2 wsH[11];      // (W[i], W[i])
#pragma unroll
    for (int i = 0; i < 11; ++i) wsH[i] = __half2half2(__float2half(W[i]));

    const int tid = threadIdx.x;
    const int r0 = blockIdx.y * TH;
    const int c0 = blockIdx.x * TW;
    const size_t pbase = (size_t)blockIdx.z * (IMGH * IMGW);
    const float* a0 = img1 + pbase;
    const float* b0 = img2 + pbase;
    const bool fast = (blockIdx.x >= 1) & (blockIdx.x <= GX - 2) &
                      (blockIdx.y >= 1) & (blockIdx.y <= GY - 2);

    // ---- Phase 1: stage (a,b) f16 pairs, zero-padded halo ----
    // 840 cells: 42 rows x 20 col-quads; LDS col l <-> image col c0-8+l.
    // float4 groups are fully in- or out-of-bounds (gc multiple of 4).
    for (int t = tid; t < HRR * 20; t += 512) {
        int row = (unsigned)t / 20u;
        int cq  = t - row * 20;
        int gr  = r0 - 5 + row;
        int gc  = c0 - 8 + 4 * cq;
        __half2 h0, h1, h2, h3;
        if (fast || ((unsigned)gr < IMGH && (unsigned)gc < IMGW)) {
            const float4 va = *reinterpret_cast<const float4*>(
                a0 + (size_t)gr * IMGW + gc);
            const float4 vb = *reinterpret_cast<const float4*>(
                b0 + (size_t)gr * IMGW + gc);
            h0 = pkrtz(va.x, vb.x);
            h1 = pkrtz(va.y, vb.y);
            h2 = pkrtz(va.z, vb.z);
            h3 = pkrtz(va.w, vb.w);
        } else {
            h0 = h1 = h2 = h3 = __half2half2(__float2half(0.f));
        }
        float4 st;
        reinterpret_cast<__half2*>(&st)[0] = h0;
        reinterpret_cast<__half2*>(&st)[1] = h1;
        reinterpret_cast<__half2*>(&st)[2] = h2;
        reinterpret_cast<__half2*>(&st)[3] = h3;
        *reinterpret_cast<float4*>(&sAB[row][4 * cq]) = st;
    }
    __syncthreads();

    // ---- Phase 2: horizontal conv, 8 out cols/item, branch-free ----
    if (tid < HRR * 8) {
        const int row = tid >> 3;
        const int cg  = tid & 7;
        const __half2* pr = &sAB[row][8 * cg];

        __half2 A[24];                 // cols 8cg .. 8cg+23
#pragma unroll
        for (int q = 0; q < 6; ++q)
            *reinterpret_cast<float4*>(&A[4 * q]) =
                *reinterpret_cast<const float4*>(&pr[4 * q]);

        __half2 accAB[8], accQC[8];
        const __half2 z2 = __half2half2(__float2half(0.f));
#pragma unroll
        for (int m = 0; m < 8; ++m) { accAB[m] = z2; accQC[m] = z2; }
#pragma unroll
        for (int t = 0; t < 18; ++t) {
            __half2 ab = A[t + 3];
            __half2 q2 = __hmul2(ab, ab);                       // (aa, bb)
            __half2 qc = __halves2half2(
                __hadd(__low2half(q2), __high2half(q2)),        // aa+bb
                __hmul(__low2half(ab), __high2half(ab)));       // ab
#pragma unroll
            for (int m = 0; m < 8; ++m) {
                int k = t - m;
                if (k >= 0 && k <= 10) {
                    accAB[m] = __hfma2(wsH[k], ab, accAB[m]);
                    accQC[m] = __hfma2(wsH[k], qc, accQC[m]);
                }
            }
        }
        // paired stores: 4 x b128 (two H4 each)
#pragma unroll
        for (int m = 0; m < 8; m += 2) {
            float4 st;
            reinterpret_cast<__half2*>(&st)[0] = accAB[m];
            reinterpret_cast<__half2*>(&st)[1] = accQC[m];
            reinterpret_cast<__half2*>(&st)[2] = accAB[m + 1];
            reinterpret_cast<__half2*>(&st)[3] = accQC[m + 1];
            *reinterpret_cast<float4*>(&sPm[row][8 * cg + m]) = st;
        }
    }
    __syncthreads();

    // ---- Phase 3: vertical conv, 1 col x 4 rows per thread ----
    const int col = tid & 63;
    const int rbase = (tid >> 6) * 4;      // 0,4,...,28 ; out rows rbase..+3
    const H4* pm = &sPm[rbase][col];

    __half2 mAB[4], mQC[4];
    {
        const __half2 z2 = __half2half2(__float2half(0.f));
#pragma unroll
        for (int r = 0; r < 4; ++r) { mAB[r] = z2; mQC[r] = z2; }
    }
#pragma unroll
    for (int j = 0; j < 14; ++j) {
        H4 h = pm[j * 64];                 // imm offset j*512B
#pragma unroll
        for (int r = 0; r < 4; ++r) {
            int i = j - r;
            if (i >= 0 && i <= 10) {
                mAB[r] = __hfma2(wsH[i], h.ab, mAB[r]);
                mQC[r] = __hfma2(wsH[i], h.qc, mQC[r]);
            }
        }
    }

    float lsum = 0.f;
#pragma unroll
    for (int r = 0; r < 4; ++r) {
        float2 m12 = __half22float2(mAB[r]);
        float2 qc  = __half22float2(mQC[r]);   // (E[aa]+E[bb], E[ab])
        float mu1 = m12.x, mu2 = m12.y;
        float mu11 = mu1 * mu1, mu22 = mu2 * mu2, mu12 = mu1 * mu2;
        float s12 = qc.y - mu12;
        float num = (2.f * mu12 + C1F) * (2.f * s12 + C2F);
        float den = (mu11 + mu22 + C1F) * ((qc.x - mu11 - mu22) + C2F);
        lsum += num * __builtin_amdgcn_rcpf(den);
    }

    // ---- Deterministic block reduction (8 waves) ----
#pragma unroll
    for (int off = 32; off > 0; off >>= 1) lsum += __shfl_down(lsum, off, 64);
    if ((tid & 63) == 0) wsum[tid >> 6] = lsum;
    __syncthreads();
    if (tid == 0) {
        float t = 0.f;
#pragma unroll
        for (int w = 0; w < 8; ++w) t += wsum[w];
        partials[((size_t)blockIdx.z * GY + blockIdx.y) * GX + blockIdx.x] = t;
    }
}

__global__ __launch_bounds__(1024)
void ssim_reduce(const float* __restrict__ partials, float* __restrict__ out, int n) {
    __shared__ float lds[1024];
    float s = 0.f;
    for (int i = threadIdx.x; i < n; i += 1024) s += partials[i];
    lds[threadIdx.x] = s;
    __syncthreads();
    for (int off = 512; off > 0; off >>= 1) {
        if ((int)threadIdx.x < off) lds[threadIdx.x] += lds[threadIdx.x + off];
        __syncthreads();
    }
    if (threadIdx.x == 0) out[0] = 1.f - lds[0] / (float)NPIX;
}

extern "C" void kernel_launch(void* const* d_in, const int* in_sizes, int n_in,
                              void* d_out, int out_size, void* d_ws, size_t ws_size,
                              hipStream_t stream) {
    const float* img1 = (const float*)d_in[0];
    const float* img2 = (const float*)d_in[1];
    float* out = (float*)d_out;
    float* partials = (float*)d_ws;

    dim3 grid(GX, GY, GZ);
    ssim_tile<<<grid, 512, 0, stream>>>(img1, img2, partials);
    ssim_reduce<<<1, 1024, 0, stream>>>(partials, out, NBLOCKS);
}